// Round 1
// baseline (43.142 us; speedup 1.0000x reference)
//
#include <hip/hip_runtime.h>

#define S 2048
#define B 32
#define CHUNKS 8          // blocks per batch row
#define IPB (S / CHUNKS)  // 256 i-values per block
#define NEPS 1e-8f

__device__ __forceinline__ float sgnf(float x) {
    return (x > 0.f ? 1.f : 0.f) - (x < 0.f ? 1.f : 0.f);
}

// ws layout (floats):
// [0] sumsq_mz  [1] sumsq_int  [2] sign_mz_sum  [3] sign_int_sum
// [4] max|mz| (as uint bits)   [5] max|intensity| (as uint bits)
// [8..39]  per-row soft_intersect
// [40..71] per-row union count
__global__ __launch_bounds__(256) void loss_main(
    const float* __restrict__ pred_mz, const float* __restrict__ mz,
    const float* __restrict__ intensity, const float* __restrict__ pred_intensity,
    float* __restrict__ ws)
{
    __shared__ __align__(16) float smz[S];
    __shared__ float red[4][8];

    const int b     = blockIdx.x >> 3;
    const int chunk = blockIdx.x & 7;
    const int tid   = threadIdx.x;

    const float* mzrow = mz + b * S;

    // stage masked mz row into LDS (masked-out entries become 0.0 and DO
    // participate in the min, matching the reference's where(mask, mz, 0))
    for (int k = tid; k < S; k += 256) {
        float m = mzrow[k];
        smz[k] = (m >= 0.f) ? m : 0.f;
    }
    __syncthreads();

    const int i  = chunk * IPB + tid;
    const int gi = b * S + i;
    const float pmz = pred_mz[gi];
    const float tmz = mzrow[i];
    const float pin = pred_intensity[gi];
    const float tin = intensity[gi];

    const float a = (pmz >= 0.f) ? pmz : 0.f;

    // min_j |a - mzm[j]| ; 4 independent accumulators to break the min chain
    float m0 = 1e30f, m1 = 1e30f, m2 = 1e30f, m3 = 1e30f;
    const float4* s4 = (const float4*)smz;
    #pragma unroll 8
    for (int j = 0; j < S / 4; ++j) {
        float4 v = s4[j];
        m0 = fminf(m0, fabsf(a - v.x));
        m1 = fminf(m1, fabsf(a - v.y));
        m2 = fminf(m2, fabsf(a - v.z));
        m3 = fminf(m3, fabsf(a - v.w));
    }
    float mind = fminf(fminf(m0, m1), fminf(m2, m3));
    float soft_match = expf(-mind * 10.0f);  // exp(-min/0.1)

    float vals[6];
    vals[0] = (pmz >= 0.f) ? soft_match * pin : 0.f;                      // intersect
    vals[1] = (pmz >= 0.f ? 1.f : 0.f) + (tmz >= 0.f ? 1.f : 0.f);        // union
    float d0 = pmz - tmz; vals[2] = d0 * d0;                              // mse mz
    float d1 = pin - tin; vals[3] = d1 * d1;                              // mse int
    vals[4] = fabsf(sgnf(pmz) - sgnf(tmz));                               // sign mz
    vals[5] = fabsf(sgnf(pin) - sgnf(tin));                               // sign int
    float vmax0 = fabsf(tmz);
    float vmax1 = fabsf(tin);

    // wave-level reduction (64 lanes)
    #pragma unroll
    for (int off = 32; off; off >>= 1) {
        #pragma unroll
        for (int k = 0; k < 6; ++k) vals[k] += __shfl_down(vals[k], off, 64);
        vmax0 = fmaxf(vmax0, __shfl_down(vmax0, off, 64));
        vmax1 = fmaxf(vmax1, __shfl_down(vmax1, off, 64));
    }

    const int lane = tid & 63, w = tid >> 6;
    if (lane == 0) {
        #pragma unroll
        for (int k = 0; k < 6; ++k) red[w][k] = vals[k];
        red[w][6] = vmax0;
        red[w][7] = vmax1;
    }
    __syncthreads();

    if (tid == 0) {
        float s[8];
        #pragma unroll
        for (int k = 0; k < 8; ++k) s[k] = red[0][k];
        #pragma unroll
        for (int wv = 1; wv < 4; ++wv) {
            #pragma unroll
            for (int k = 0; k < 6; ++k) s[k] += red[wv][k];
            s[6] = fmaxf(s[6], red[wv][6]);
            s[7] = fmaxf(s[7], red[wv][7]);
        }
        atomicAdd(&ws[8 + b],  s[0]);
        atomicAdd(&ws[40 + b], s[1]);
        atomicAdd(&ws[0], s[2]);
        atomicAdd(&ws[1], s[3]);
        atomicAdd(&ws[2], s[4]);
        atomicAdd(&ws[3], s[5]);
        atomicMax((unsigned int*)&ws[4], __float_as_uint(s[6]));
        atomicMax((unsigned int*)&ws[5], __float_as_uint(s[7]));
    }
}

__global__ __launch_bounds__(64) void loss_finalize(const float* __restrict__ ws,
                                                    float* __restrict__ out)
{
    const int lane = threadIdx.x;
    float jl = 0.f;
    if (lane < B) {
        float I = ws[8 + lane];
        float U = ws[40 + lane];
        jl = 1.f - (I + NEPS) / (U + NEPS);
    }
    #pragma unroll
    for (int off = 32; off; off >>= 1) jl += __shfl_down(jl, off, 64);

    if (lane == 0) {
        const float inv_n = 1.0f / (float)(B * S);
        float max_mz  = __uint_as_float(((const unsigned int*)ws)[4]);
        float max_int = __uint_as_float(((const unsigned int*)ws)[5]);
        out[0] = jl / (float)B;
        out[1] = (ws[0] * inv_n) / (max_mz * max_mz);
        out[2] = (ws[1] * inv_n) / (max_int * max_int);
        out[3] = (ws[2] * inv_n + ws[3] * inv_n) * 0.5f;
    }
}

extern "C" void kernel_launch(void* const* d_in, const int* in_sizes, int n_in,
                              void* d_out, int out_size, void* d_ws, size_t ws_size,
                              hipStream_t stream) {
    const float* pred_mz        = (const float*)d_in[0];
    const float* mz             = (const float*)d_in[1];
    const float* intensity      = (const float*)d_in[2];
    const float* pred_intensity = (const float*)d_in[3];
    float* out = (float*)d_out;
    float* ws  = (float*)d_ws;

    hipMemsetAsync(ws, 0, 72 * sizeof(float), stream);
    loss_main<<<B * CHUNKS, 256, 0, stream>>>(pred_mz, mz, intensity, pred_intensity, ws);
    loss_finalize<<<1, 64, 0, stream>>>(ws, out);
}

// Round 2
// 14.346 us; speedup vs baseline: 3.0073x; 3.0073x over previous
//
#include <hip/hip_runtime.h>

#define S 2048
#define B 32
#define NEPS 1e-8f
// grid: B rows x 32 chunks = 1024 blocks; block = 256 threads (4 waves)
// each block: 64 i-values; j-range split across the 4 waves (512 j each)

__device__ __forceinline__ float sgnf(float x) {
    return (x > 0.f ? 1.f : 0.f) - (x < 0.f ? 1.f : 0.f);
}

// ws: per-block partials, 8 floats each:
// [0]=intersect [1]=union [2]=ssq_mz [3]=ssq_int [4]=sgn_mz [5]=sgn_int [6]=max|mz| [7]=max|int|
__global__ __launch_bounds__(256, 4) void loss_main(
    const float* __restrict__ pred_mz, const float* __restrict__ mz,
    const float* __restrict__ intensity, const float* __restrict__ pred_intensity,
    float* __restrict__ ws)
{
    __shared__ __align__(16) float smz[S];
    __shared__ float smin[4][64];

    const int blk   = blockIdx.x;
    const int b     = blk >> 5;    // row
    const int chunk = blk & 31;    // which 64-i chunk
    const int tid   = threadIdx.x;
    const int lane  = tid & 63;
    const int w     = tid >> 6;

    const float* mzrow = mz + b * S;

    // stage masked mz row (masked-out -> 0.0, participates in min per reference)
    {
        const float4* g4 = (const float4*)mzrow;
        float4* l4 = (float4*)smz;
        #pragma unroll
        for (int r = 0; r < 2; ++r) {
            int k = tid + 256 * r;
            float4 v = g4[k];
            v.x = (v.x >= 0.f) ? v.x : 0.f;
            v.y = (v.y >= 0.f) ? v.y : 0.f;
            v.z = (v.z >= 0.f) ? v.z : 0.f;
            v.w = (v.w >= 0.f) ? v.w : 0.f;
            l4[k] = v;
        }
    }
    __syncthreads();

    const int i   = chunk * 64 + lane;
    const int gi  = b * S + i;
    const float pmz = pred_mz[gi];
    const float a   = (pmz >= 0.f) ? pmz : 0.f;

    // this wave's j-quarter: 512 floats = 128 float4
    float m0 = 1e30f, m1 = 1e30f, m2 = 1e30f, m3 = 1e30f;
    const float4* s4 = (const float4*)smz + w * 128;
    #pragma unroll 4
    for (int j = 0; j < 128; ++j) {
        float4 v = s4[j];
        m0 = fminf(m0, fabsf(a - v.x));
        m1 = fminf(m1, fabsf(a - v.y));
        m2 = fminf(m2, fabsf(a - v.z));
        m3 = fminf(m3, fabsf(a - v.w));
    }
    smin[w][lane] = fminf(fminf(m0, m1), fminf(m2, m3));
    __syncthreads();

    if (tid < 64) {
        float mind = fminf(fminf(smin[0][lane], smin[1][lane]),
                           fminf(smin[2][lane], smin[3][lane]));
        float sm = exp2f(mind * -14.426950408889634f);  // exp(-mind/0.1)

        const float tmz = mzrow[i];
        const float pin = pred_intensity[gi];
        const float tin = intensity[gi];

        float vals[6];
        vals[0] = (pmz >= 0.f) ? sm * pin : 0.f;
        vals[1] = (pmz >= 0.f ? 1.f : 0.f) + (tmz >= 0.f ? 1.f : 0.f);
        float d0 = pmz - tmz; vals[2] = d0 * d0;
        float d1 = pin - tin; vals[3] = d1 * d1;
        vals[4] = fabsf(sgnf(pmz) - sgnf(tmz));
        vals[5] = fabsf(sgnf(pin) - sgnf(tin));
        float vmax0 = fabsf(tmz);
        float vmax1 = fabsf(tin);

        #pragma unroll
        for (int off = 32; off; off >>= 1) {
            #pragma unroll
            for (int k = 0; k < 6; ++k) vals[k] += __shfl_down(vals[k], off, 64);
            vmax0 = fmaxf(vmax0, __shfl_down(vmax0, off, 64));
            vmax1 = fmaxf(vmax1, __shfl_down(vmax1, off, 64));
        }
        if (lane == 0) {
            float* p = ws + blk * 8;
            p[0] = vals[0]; p[1] = vals[1]; p[2] = vals[2]; p[3] = vals[3];
            p[4] = vals[4]; p[5] = vals[5]; p[6] = vmax0;   p[7] = vmax1;
        }
    }
}

__global__ __launch_bounds__(256) void loss_finalize(const float* __restrict__ ws,
                                                     float* __restrict__ out)
{
    __shared__ float red[4][7];
    const int t    = threadIdx.x;       // 0..255, thread t covers blocks t*4..t*4+3
    const int lane = t & 63;
    const int w    = t >> 6;

    float I = 0.f, U = 0.f, s2 = 0.f, s3 = 0.f, s4 = 0.f, s5 = 0.f;
    float mx0 = 0.f, mx1 = 0.f;
    #pragma unroll
    for (int k = 0; k < 4; ++k) {
        const float* p = ws + (t * 4 + k) * 8;
        I  += p[0]; U  += p[1];
        s2 += p[2]; s3 += p[3];
        s4 += p[4]; s5 += p[5];
        mx0 = fmaxf(mx0, p[6]); mx1 = fmaxf(mx1, p[7]);
    }
    // 8 consecutive threads share a row -> reduce I,U within groups of 8
    #pragma unroll
    for (int off = 4; off; off >>= 1) {
        I += __shfl_down(I, off, 8);
        U += __shfl_down(U, off, 8);
    }
    float jl = ((t & 7) == 0) ? (1.f - (I + NEPS) / (U + NEPS)) : 0.f;

    #pragma unroll
    for (int off = 32; off; off >>= 1) {
        jl += __shfl_down(jl, off, 64);
        s2 += __shfl_down(s2, off, 64);
        s3 += __shfl_down(s3, off, 64);
        s4 += __shfl_down(s4, off, 64);
        s5 += __shfl_down(s5, off, 64);
        mx0 = fmaxf(mx0, __shfl_down(mx0, off, 64));
        mx1 = fmaxf(mx1, __shfl_down(mx1, off, 64));
    }
    if (lane == 0) {
        red[w][0] = jl; red[w][1] = s2; red[w][2] = s3;
        red[w][3] = s4; red[w][4] = s5; red[w][5] = mx0; red[w][6] = mx1;
    }
    __syncthreads();
    if (t == 0) {
        float fjl = red[0][0], f2 = red[0][1], f3 = red[0][2], f4 = red[0][3],
              f5 = red[0][4], fm0 = red[0][5], fm1 = red[0][6];
        #pragma unroll
        for (int wv = 1; wv < 4; ++wv) {
            fjl += red[wv][0]; f2 += red[wv][1]; f3 += red[wv][2];
            f4  += red[wv][3]; f5 += red[wv][4];
            fm0 = fmaxf(fm0, red[wv][5]); fm1 = fmaxf(fm1, red[wv][6]);
        }
        const float inv_n = 1.0f / (float)(B * S);
        out[0] = fjl / (float)B;
        out[1] = (f2 * inv_n) / (fm0 * fm0);
        out[2] = (f3 * inv_n) / (fm1 * fm1);
        out[3] = (f4 + f5) * inv_n * 0.5f;
    }
}

extern "C" void kernel_launch(void* const* d_in, const int* in_sizes, int n_in,
                              void* d_out, int out_size, void* d_ws, size_t ws_size,
                              hipStream_t stream) {
    const float* pred_mz        = (const float*)d_in[0];
    const float* mz             = (const float*)d_in[1];
    const float* intensity      = (const float*)d_in[2];
    const float* pred_intensity = (const float*)d_in[3];
    float* out = (float*)d_out;
    float* ws  = (float*)d_ws;

    loss_main<<<B * 32, 256, 0, stream>>>(pred_mz, mz, intensity, pred_intensity, ws);
    loss_finalize<<<1, 256, 0, stream>>>(ws, out);
}

// Round 3
// 13.818 us; speedup vs baseline: 3.1221x; 1.0382x over previous
//
#include <hip/hip_runtime.h>

#define S 2048
#define B 32
#define NEPS 1e-8f
// grid: 32 rows x 16 chunks = 512 blocks; block = 256 threads (4 waves)
// each block: 128 i-values (2 per thread); j-range split across 4 waves (512 j each)

__device__ __forceinline__ float sgnf(float x) {
    return (x > 0.f ? 1.f : 0.f) - (x < 0.f ? 1.f : 0.f);
}

// ws: per-block partials, 8 floats each:
// [0]=intersect [1]=union [2]=ssq_mz [3]=ssq_int [4]=sgn_mz [5]=sgn_int [6]=max|mz| [7]=max|int|
__global__ __launch_bounds__(256, 2) void loss_main(
    const float* __restrict__ pred_mz, const float* __restrict__ mz,
    const float* __restrict__ intensity, const float* __restrict__ pred_intensity,
    float* __restrict__ ws)
{
    __shared__ __align__(16) float smz[S];
    __shared__ float smin[4][128];
    __shared__ float red[4][8];

    const int blk   = blockIdx.x;
    const int b     = blk >> 4;    // row
    const int chunk = blk & 15;    // which 128-i chunk
    const int tid   = threadIdx.x;
    const int lane  = tid & 63;
    const int w     = tid >> 6;

    const float* mzrow = mz + b * S;

    // stage masked mz row (masked-out -> 0.0, participates in min per reference)
    {
        const float4* g4 = (const float4*)mzrow;
        float4* l4 = (float4*)smz;
        #pragma unroll
        for (int r = 0; r < 2; ++r) {
            int k = tid + 256 * r;
            float4 v = g4[k];
            v.x = (v.x >= 0.f) ? v.x : 0.f;
            v.y = (v.y >= 0.f) ? v.y : 0.f;
            v.z = (v.z >= 0.f) ? v.z : 0.f;
            v.w = (v.w >= 0.f) ? v.w : 0.f;
            l4[k] = v;
        }
    }
    __syncthreads();

    // two i-values per thread: i0 = chunk*128 + lane, i1 = i0 + 64
    const int i0  = chunk * 128 + lane;
    const int gi0 = b * S + i0;
    const float p0 = pred_mz[gi0];
    const float p1 = pred_mz[gi0 + 64];
    const float a0 = (p0 >= 0.f) ? p0 : 0.f;
    const float a1 = (p1 >= 0.f) ? p1 : 0.f;

    // this wave's j-quarter: 512 floats = 128 float4; uniform (broadcast) reads
    float m00 = 1e30f, m01 = 1e30f, m10 = 1e30f, m11 = 1e30f;
    const float4* s4 = (const float4*)smz + w * 128;
    #pragma unroll 8
    for (int j = 0; j < 128; ++j) {
        float4 v = s4[j];
        float d0 = a0 - v.x, d1 = a0 - v.y, d2 = a0 - v.z, d3 = a0 - v.w;
        m00 = fminf(fminf(m00, fabsf(d0)), fabsf(d1));   // -> v_min3 w/ abs mods
        m01 = fminf(fminf(m01, fabsf(d2)), fabsf(d3));
        float e0 = a1 - v.x, e1 = a1 - v.y, e2 = a1 - v.z, e3 = a1 - v.w;
        m10 = fminf(fminf(m10, fabsf(e0)), fabsf(e1));
        m11 = fminf(fminf(m11, fabsf(e2)), fabsf(e3));
    }
    smin[w][lane]      = fminf(m00, m01);
    smin[w][lane + 64] = fminf(m10, m11);
    __syncthreads();

    // tail: threads 0..127 finish one i each; others contribute identity
    float vals[6] = {0.f, 0.f, 0.f, 0.f, 0.f, 0.f};
    float vmax0 = 0.f, vmax1 = 0.f;
    if (tid < 128) {
        float mind = fminf(fminf(smin[0][tid], smin[1][tid]),
                           fminf(smin[2][tid], smin[3][tid]));
        float sm = exp2f(mind * -14.426950408889634f);  // exp(-mind/0.1)

        const int i  = chunk * 128 + tid;
        const int gi = b * S + i;
        const float pmz = pred_mz[gi];
        const float tmz = mzrow[i];
        const float pin = pred_intensity[gi];
        const float tin = intensity[gi];

        vals[0] = (pmz >= 0.f) ? sm * pin : 0.f;
        vals[1] = (pmz >= 0.f ? 1.f : 0.f) + (tmz >= 0.f ? 1.f : 0.f);
        float d0 = pmz - tmz; vals[2] = d0 * d0;
        float d1 = pin - tin; vals[3] = d1 * d1;
        vals[4] = fabsf(sgnf(pmz) - sgnf(tmz));
        vals[5] = fabsf(sgnf(pin) - sgnf(tin));
        vmax0 = fabsf(tmz);
        vmax1 = fabsf(tin);
    }

    #pragma unroll
    for (int off = 32; off; off >>= 1) {
        #pragma unroll
        for (int k = 0; k < 6; ++k) vals[k] += __shfl_down(vals[k], off, 64);
        vmax0 = fmaxf(vmax0, __shfl_down(vmax0, off, 64));
        vmax1 = fmaxf(vmax1, __shfl_down(vmax1, off, 64));
    }
    if (lane == 0) {
        #pragma unroll
        for (int k = 0; k < 6; ++k) red[w][k] = vals[k];
        red[w][6] = vmax0;
        red[w][7] = vmax1;
    }
    __syncthreads();

    if (tid == 0) {
        float s[8];
        #pragma unroll
        for (int k = 0; k < 8; ++k) s[k] = red[0][k];
        #pragma unroll
        for (int wv = 1; wv < 4; ++wv) {
            #pragma unroll
            for (int k = 0; k < 6; ++k) s[k] += red[wv][k];
            s[6] = fmaxf(s[6], red[wv][6]);
            s[7] = fmaxf(s[7], red[wv][7]);
        }
        float4* p = (float4*)(ws + blk * 8);
        p[0] = make_float4(s[0], s[1], s[2], s[3]);
        p[1] = make_float4(s[4], s[5], s[6], s[7]);
    }
}

__global__ __launch_bounds__(256) void loss_finalize(const float* __restrict__ ws,
                                                     float* __restrict__ out)
{
    __shared__ float red[4][7];
    const int t    = threadIdx.x;       // thread t covers blocks 2t, 2t+1 (same row)
    const int lane = t & 63;
    const int w    = t >> 6;

    float I = 0.f, U = 0.f, s2 = 0.f, s3 = 0.f, s4 = 0.f, s5 = 0.f;
    float mx0 = 0.f, mx1 = 0.f;
    #pragma unroll
    for (int k = 0; k < 2; ++k) {
        const float4* p = (const float4*)(ws + (t * 2 + k) * 8);
        float4 lo = p[0], hi = p[1];
        I  += lo.x; U  += lo.y;
        s2 += lo.z; s3 += lo.w;
        s4 += hi.x; s5 += hi.y;
        mx0 = fmaxf(mx0, hi.z); mx1 = fmaxf(mx1, hi.w);
    }
    // 8 consecutive threads share a row (16 blocks/row) -> reduce I,U in groups of 8
    #pragma unroll
    for (int off = 4; off; off >>= 1) {
        I += __shfl_down(I, off, 8);
        U += __shfl_down(U, off, 8);
    }
    float jl = ((t & 7) == 0) ? (1.f - (I + NEPS) / (U + NEPS)) : 0.f;

    #pragma unroll
    for (int off = 32; off; off >>= 1) {
        jl += __shfl_down(jl, off, 64);
        s2 += __shfl_down(s2, off, 64);
        s3 += __shfl_down(s3, off, 64);
        s4 += __shfl_down(s4, off, 64);
        s5 += __shfl_down(s5, off, 64);
        mx0 = fmaxf(mx0, __shfl_down(mx0, off, 64));
        mx1 = fmaxf(mx1, __shfl_down(mx1, off, 64));
    }
    if (lane == 0) {
        red[w][0] = jl; red[w][1] = s2; red[w][2] = s3;
        red[w][3] = s4; red[w][4] = s5; red[w][5] = mx0; red[w][6] = mx1;
    }
    __syncthreads();
    if (t == 0) {
        float fjl = red[0][0], f2 = red[0][1], f3 = red[0][2], f4 = red[0][3],
              f5 = red[0][4], fm0 = red[0][5], fm1 = red[0][6];
        #pragma unroll
        for (int wv = 1; wv < 4; ++wv) {
            fjl += red[wv][0]; f2 += red[wv][1]; f3 += red[wv][2];
            f4  += red[wv][3]; f5 += red[wv][4];
            fm0 = fmaxf(fm0, red[wv][5]); fm1 = fmaxf(fm1, red[wv][6]);
        }
        const float inv_n = 1.0f / (float)(B * S);
        out[0] = fjl / (float)B;
        out[1] = (f2 * inv_n) / (fm0 * fm0);
        out[2] = (f3 * inv_n) / (fm1 * fm1);
        out[3] = (f4 + f5) * inv_n * 0.5f;
    }
}

extern "C" void kernel_launch(void* const* d_in, const int* in_sizes, int n_in,
                              void* d_out, int out_size, void* d_ws, size_t ws_size,
                              hipStream_t stream) {
    const float* pred_mz        = (const float*)d_in[0];
    const float* mz             = (const float*)d_in[1];
    const float* intensity      = (const float*)d_in[2];
    const float* pred_intensity = (const float*)d_in[3];
    float* out = (float*)d_out;
    float* ws  = (float*)d_ws;

    loss_main<<<B * 16, 256, 0, stream>>>(pred_mz, mz, intensity, pred_intensity, ws);
    loss_finalize<<<1, 256, 0, stream>>>(ws, out);
}